// Round 7
// baseline (2691.829 us; speedup 1.0000x reference)
//
#include <hip/hip_runtime.h>
#include <math.h>

#define N1 1024
#define NN2 (N1*N1)
#define LL 16384
#define SPLITK 8          // K split for the 1024^3 GEMMs
#define KSLAB (N1/SPLITK) // 128
#define BK 16             // k-block depth
#define NKB (KSLAB/BK)    // 8 k-blocks per slab
#define TM 256            // tile rows
#define TN 128            // tile cols
#define APAD 284          // 256 + 4-per-32 pad
#define BPAD 140          // 128 + 4-per-32 pad
#define SMEMF (2*BK*APAD + 2*BK*BPAD)  // 13568 floats = 54272 B (GEMM staging)

// ---------------- elementwise ----------------
__global__ __launch_bounds__(256) void k_scale(const float* __restrict__ A,
                                               const float* __restrict__ logd,
                                               float* __restrict__ e) {
    int i = blockIdx.x * 256 + threadIdx.x;
    float d = expf(logd[0]);
    e[i] = 0.5f * d * A[i];
}

__global__ __launch_bounds__(256) void k_add(const float* __restrict__ a,
                                             const float* __restrict__ b,
                                             float* __restrict__ o) {
    int i = blockIdx.x * 256 + threadIdx.x;
    o[i] = a[i] + b[i];
}

// ---------------- chain-partial device code (mode 0 = Q rows, 1 = P cols) --------
// NW = number of waves in the block (4 for 256-thread kernels, 8 for 512-thread).
template<int NW>
__device__ __forceinline__ void chain_part(const float* __restrict__ M,
                                           float* __restrict__ V,
                                           float* __restrict__ CP,
                                           int w, int lkc, int mode, int cb,
                                           float* sV, float (*red)[64]) {
    int kc = 1 << lkc;
    int i = cb >> (4 + lkc);
    int ky = (cb >> 4) & (kc - 1);
    int nx = cb & 15;
    int mlen = N1 >> lkc;
    int m0 = ky * mlen, n0 = nx * 64;
    int t = threadIdx.x;
    const float* Vi = V + (size_t)i * N1 + m0;
    if (t * 4 < mlen) *(float4*)&sV[t * 4] = *(const float4*)&Vi[t * 4];
    __syncthreads();
    int wave = t >> 6, lane = t & 63;
    if (mode == 0) {
        const int RR = 64 / NW;
        for (int rr = 0; rr < RR; ++rr) {
            int n = n0 + wave * RR + rr;
            const float* Mr = M + (size_t)n * N1 + m0;
            float acc = 0.f;
            for (int m = lane * 4; m < mlen; m += 256) {
                float4 a = *(const float4*)&Mr[m];
                float4 v = *(const float4*)&sV[m];
                acc += a.x * v.x + a.y * v.y + a.z * v.z + a.w * v.w;
            }
#pragma unroll
            for (int off = 32; off > 0; off >>= 1) acc += __shfl_down(acc, off, 64);
            if (lane == 0) {
                if (kc == 1) V[(size_t)(w + i) * N1 + n] = sV[n] + acc;
                else CP[((size_t)i * kc + ky) * N1 + n] = acc;
            }
        }
    } else {
        int n = n0 + lane;
        int msub = mlen / NW;
        int mb = wave * msub;
        float acc = 0.f;
#pragma unroll 8
        for (int m = 0; m < msub; ++m)
            acc += sV[mb + m] * M[(size_t)(m0 + mb + m) * N1 + n];
        red[wave][lane] = acc;
        __syncthreads();
        if (t < 64) {
            float s = 0.f;
#pragma unroll
            for (int c = 0; c < NW; ++c) s += red[c][t];
            if (kc == 1) V[(size_t)(w + i) * N1 + n0 + t] = sV[n0 + t] + s;
            else CP[((size_t)i * kc + ky) * N1 + n0 + t] = s;
        }
    }
}

// ========== fused dispatch: [chain blocks | 256 SGEMM blocks], 512 threads ==========
// GEMM: part[z] = Ain[:, z*128:(z+1)*128] @ Bin[z*128:..., :]
// 256x128 tile, BK=16, 8x8 microtile, 8 waves/block = 2 waves/SIMD guaranteed.
//
// ROUNDS 4-6 LESSON: the backend derives its occupancy TARGET from LDS
// (160K/54272B = 2 WGs = 4 waves/EU) and budgets VGPRs to match (512/4 = 128),
// spilling the ~190-VGPR accumulator (660 MB/dispatch scratch traffic).
// __launch_bounds__'s 2nd arg is a MINIMUM waves/EU — it cannot lower the
// LDS-derived target. amdgpu_waves_per_eu(2,2) pins the MAX too -> 256-VGPR
// budget -> spill-free.
__global__ __launch_bounds__(512) __attribute__((amdgpu_waves_per_eu(2, 2)))
void k_fused(const float* __restrict__ Ain,
             const float* __restrict__ Bin,
             float* __restrict__ part,
             float* __restrict__ V,
             float* __restrict__ CP,
             int w, int lkc, int nchain, int mode) {
    // LDS overlay: GEMM uses As/Bs (54272 B); chain path uses sV/red (6144 B).
    __shared__ __align__(16) float smem[SMEMF];
    float (*As)[BK][APAD] = (float(*)[BK][APAD])smem;
    float (*Bs)[BK][BPAD] = (float(*)[BK][BPAD])(smem + 2*BK*APAD);
    int b = blockIdx.x;
    if (b < nchain) {
        float* sV = smem;
        float (*red)[64] = (float(*)[64])(smem + N1);
        chain_part<8>(Ain, V, CP, w, lkc, mode, b, sV, red);
        return;
    }
    int g = b - nchain;
    int t = threadIdx.x;
    int z = g >> 5;
    int tile = g & 31;
    int m0 = (tile >> 3) * TM, n0 = (tile & 7) * TN, kz = z * KSLAB;
    int tx = t & 15, ty = t >> 4;

    // global-load mapping: A 256 rows x 16 k (8 floats/thread), B 16 k x 128 cols (4/thread)
    int arow = t >> 1, acol = (t & 1) * 8;
    int brow = t >> 5, bcol = (t & 31) * 4;
    const float* Ap = Ain + (size_t)(m0 + arow) * N1 + kz + acol;
    const float* Bp = Bin + (size_t)(kz + brow) * N1 + n0 + bcol;

    // padded physical indices
    int aphys  = arow + ((arow >> 5) << 2);
    int bphysW = bcol + ((bcol >> 5) << 2);
    int afrag  = ty * 8 + ((ty >> 2) << 2);
    int bfrag  = tx * 8 + ((tx >> 2) << 2);

    { // prologue: stage k-block 0
        float4 a0 = *(const float4*)(Ap);
        float4 a1 = *(const float4*)(Ap + 4);
        float4 b0 = *(const float4*)(Bp);
        As[0][acol + 0][aphys] = a0.x; As[0][acol + 1][aphys] = a0.y;
        As[0][acol + 2][aphys] = a0.z; As[0][acol + 3][aphys] = a0.w;
        As[0][acol + 4][aphys] = a1.x; As[0][acol + 5][aphys] = a1.y;
        As[0][acol + 6][aphys] = a1.z; As[0][acol + 7][aphys] = a1.w;
        *(float4*)&Bs[0][brow][bphysW] = b0;
    }
    __syncthreads();

    float acc[8][8];
#pragma unroll
    for (int i = 0; i < 8; ++i)
#pragma unroll
        for (int j = 0; j < 8; ++j) acc[i][j] = 0.f;

    for (int kb = 0; kb < NKB; ++kb) {
        int cur = kb & 1;
        float4 na0, na1, nb0;
        if (kb < NKB - 1) {
            int ko = (kb + 1) * BK;
            na0 = *(const float4*)(Ap + ko);
            na1 = *(const float4*)(Ap + ko + 4);
            nb0 = *(const float4*)(Bp + (size_t)ko * N1);
        }
#pragma unroll
        for (int k = 0; k < BK; ++k) {
            float4 xa0 = *(float4*)&As[cur][k][afrag];
            float4 xa1 = *(float4*)&As[cur][k][afrag + 4];
            float4 xb0 = *(float4*)&Bs[cur][k][bfrag];
            float4 xb1 = *(float4*)&Bs[cur][k][bfrag + 4];
            float av[8] = {xa0.x, xa0.y, xa0.z, xa0.w, xa1.x, xa1.y, xa1.z, xa1.w};
            float bv[8] = {xb0.x, xb0.y, xb0.z, xb0.w, xb1.x, xb1.y, xb1.z, xb1.w};
#pragma unroll
            for (int i = 0; i < 8; ++i)
#pragma unroll
                for (int j = 0; j < 8; ++j) acc[i][j] += av[i] * bv[j];
        }
        if (kb < NKB - 1) {
            int nx2 = cur ^ 1;
            As[nx2][acol + 0][aphys] = na0.x; As[nx2][acol + 1][aphys] = na0.y;
            As[nx2][acol + 2][aphys] = na0.z; As[nx2][acol + 3][aphys] = na0.w;
            As[nx2][acol + 4][aphys] = na1.x; As[nx2][acol + 5][aphys] = na1.y;
            As[nx2][acol + 6][aphys] = na1.z; As[nx2][acol + 7][aphys] = na1.w;
            *(float4*)&Bs[nx2][brow][bphysW] = nb0;
            __syncthreads();
        }
    }

    float* Po = part + (size_t)z * NN2;
#pragma unroll
    for (int i = 0; i < 8; ++i) {
        float4 o0 = {acc[i][0], acc[i][1], acc[i][2], acc[i][3]};
        float4 o1 = {acc[i][4], acc[i][5], acc[i][6], acc[i][7]};
        size_t ro = (size_t)(m0 + ty * 8 + i) * N1 + n0 + tx * 8;
        *(float4*)&Po[ro]     = o0;
        *(float4*)&Po[ro + 4] = o1;
    }
}

// ---------------- chain-partial-only dispatch (init Q0, final P step), 256 thr ----
__global__ __launch_bounds__(256) void k_cpart(const float* __restrict__ M,
                                               float* __restrict__ V,
                                               float* __restrict__ CP,
                                               int w, int lkc, int mode) {
    __shared__ float sV[N1];
    __shared__ float red[4][64];
    chain_part<4>(M, V, CP, w, lkc, mode, blockIdx.x, sV, red);
}

// ---------------- fused reduce: [1024 mmred blocks | 4w chainR blocks] ------------
// mmred: Cout = alpha*sum(part[0..nparts)) + beta*Aadd
__global__ __launch_bounds__(256) void k_redu(const float* __restrict__ part,
                                              const float* __restrict__ Aadd,
                                              float* __restrict__ C,
                                              float alpha, float beta,
                                              float* __restrict__ V,
                                              const float* __restrict__ CP,
                                              int w, int kc, int nparts) {
    int b = blockIdx.x, t = threadIdx.x;
    if (b < 1024) {
        int i = (b * 256 + t) * 4;
        float sx = 0.f, sy = 0.f, sz = 0.f, sw = 0.f;
        for (int c = 0; c < nparts; ++c) {
            float4 p = *(const float4*)&part[(size_t)c * NN2 + i];
            sx += p.x; sy += p.y; sz += p.z; sw += p.w;
        }
        float4 av = *(const float4*)&Aadd[i];
        float4 o;
        o.x = alpha * sx + beta * av.x;
        o.y = alpha * sy + beta * av.y;
        o.z = alpha * sz + beta * av.z;
        o.w = alpha * sw + beta * av.w;
        *(float4*)&C[i] = o;
    } else {
        int rb = b - 1024;
        int i = rb >> 2;
        int n = (rb & 3) * 256 + t;
        const float* pp = CP + (size_t)i * kc * N1 + n;
        float s = 0.f;
        for (int c = 0; c < kc; ++c) s += pp[(size_t)c * N1];
        V[(size_t)(w + i) * N1 + n] = V[(size_t)i * N1 + n] + s;
    }
}

// ---------------- init reduce: Q[0] = d*(B + 0.5*D1@B); P[0] = C ----------------
__global__ __launch_bounds__(256) void k_initR(const float* __restrict__ Bv,
                                               const float* __restrict__ Cv,
                                               const float* __restrict__ logd,
                                               const float* __restrict__ part,
                                               float* __restrict__ Q,
                                               float* __restrict__ P) {
    int n = blockIdx.x * 256 + threadIdx.x;
    float s = 0.f;
    for (int c = 0; c < 16; ++c) s += part[(size_t)c * N1 + n];
    float d = expf(logd[0]);
    Q[n] = d * (Bv[n] + 0.5f * s);
    P[n] = Cv[n];
}

// ---------------- K[a*128+b] = dot(P[a], Q[b]) ----------------
__global__ __launch_bounds__(256) void k_kdot(const float* __restrict__ P,
                                              const float* __restrict__ Q,
                                              float* __restrict__ K) {
    int t = threadIdx.x;
    int wid = blockIdx.x * 4 + (t >> 6), lane = t & 63;
    int a = wid >> 7, b = wid & 127;
    const float* Pr = P + (size_t)a * N1;
    const float* Qr = Q + (size_t)b * N1;
    float acc = 0.f;
#pragma unroll
    for (int jj = 0; jj < 4; ++jj) {
        int m = jj * 256 + lane * 4;
        float4 p = *(const float4*)&Pr[m];
        float4 q = *(const float4*)&Qr[m];
        acc += p.x * q.x + p.y * q.y + p.z * q.z + p.w * q.w;
    }
#pragma unroll
    for (int off = 32; off > 0; off >>= 1) acc += __shfl_down(acc, off, 64);
    if (lane == 0) K[wid] = acc;
}

// ---------------- conv phase 1 ----------------
__global__ __launch_bounds__(256) void k_conv1(const float* __restrict__ X,
                                               const float* __restrict__ K,
                                               float* __restrict__ part) {
    __shared__ __align__(16) float ks[1280];
    __shared__ __align__(16) float xs[256];
    int bx = blockIdx.x, tt = threadIdx.x;
    int o = 0;
    while (bx >= 2 * (o + 1) * (o + 1) + 2 * (o + 1)) ++o;
    int jt = bx - (2 * o * o + 2 * o);
    int T0 = o * 1024, J0 = jt * 256;
    int mb = T0 - J0 - 255;
    for (int ii = tt; ii < 1280; ii += 256) {
        int m = mb + ii;
        ks[ii] = (m >= 0 && m < LL) ? K[m] : 0.f;
    }
    xs[tt] = X[J0 + tt];
    __syncthreads();

    float acc0 = 0.f, acc1 = 0.f, acc2 = 0.f, acc3 = 0.f;
    int base0 = 4 * tt + 252;
#pragma unroll 4
    for (int jj = 0; jj < 256; jj += 4) {
        float4 xv  = *(const float4*)&xs[jj];
        float4 kv0 = *(const float4*)&ks[base0 - jj];
        float4 kv1 = *(const float4*)&ks[base0 - jj + 4];
        float kk0 = kv0.x, kk1 = kv0.y, kk2 = kv0.z, kk3 = kv0.w;
        float kk4 = kv1.x, kk5 = kv1.y, kk6 = kv1.z;
        acc0 += kk3 * xv.x + kk2 * xv.y + kk1 * xv.z + kk0 * xv.w;
        acc1 += kk4 * xv.x + kk3 * xv.y + kk2 * xv.z + kk1 * xv.w;
        acc2 += kk5 * xv.x + kk4 * xv.y + kk3 * xv.z + kk2 * xv.w;
        acc3 += kk6 * xv.x + kk5 * xv.y + kk4 * xv.z + kk3 * xv.w;
    }
    float4 out = {acc0, acc1, acc2, acc3};
    *(float4*)&part[((size_t)(o * 64 + jt)) * 1024 + 4 * tt] = out;
}

// ---------------- conv phase 2 ----------------
__global__ __launch_bounds__(256) void k_conv2(const float* __restrict__ X,
                                               const float* __restrict__ part,
                                               const float* __restrict__ Dp,
                                               float* __restrict__ Y) {
    int o = blockIdx.x, tt = threadIdx.x;
    int c = 4 * tt;
    float s0 = 0.f, s1 = 0.f, s2 = 0.f, s3 = 0.f;
    int cnt = 4 * o + 4;
    for (int jt = 0; jt < cnt; ++jt) {
        float4 p = *(const float4*)&part[((size_t)(o * 64 + jt)) * 1024 + c];
        s0 += p.x; s1 += p.y; s2 += p.z; s3 += p.w;
    }
    float dsk = Dp[0];
    int t = o * 1024 + c;
    float4 xv = *(const float4*)&X[t];
    float4 out;
    out.x = dsk * xv.x + s0;
    out.y = dsk * xv.y + s1;
    out.z = dsk * xv.z + s2;
    out.w = dsk * xv.w + s3;
    *(float4*)&Y[t] = out;
}

extern "C" void kernel_launch(void* const* d_in, const int* in_sizes, int n_in,
                              void* d_out, int out_size, void* d_ws, size_t ws_size,
                              hipStream_t stream) {
    const float* X    = (const float*)d_in[0];
    const float* A    = (const float*)d_in[1];
    const float* Bv   = (const float*)d_in[2];
    const float* Cv   = (const float*)d_in[3];
    const float* Dp   = (const float*)d_in[4];
    const float* logd = (const float*)d_in[5];
    float* ws = (float*)d_ws;

    const int nparts = SPLITK;         // 8 (ws >= 10*NN2+extras verified in round 3)
    const int NG = 32 * SPLITK;        // 256 GEMM blocks = 1/CU

    // layout: [partials (8 x NN2)] [M1] [M2] [CP] [Q] [P] [Kc]
    float* P0 = ws;
    float* M1 = ws + (size_t)nparts * NN2;
    float* M2 = M1 + (size_t)NN2;
    float* CP = M2 + (size_t)NN2;          // chain partials (<=64 KB)
    float* Q  = CP + 64*(size_t)N1;        // 128 x 1024
    float* P  = Q + 128*(size_t)N1;        // 128 x 1024
    float* Kc = P + 128*(size_t)N1;        // 16384
    float* Y  = (float*)d_out;

    auto FUSED = [&](const float* Aq, const float* Bq, float* V, float* CPp,
                     int w, int lkc, int nchain, int mode) {
        k_fused<<<nchain + NG, 512, 0, stream>>>(Aq, Bq, P0, V, CPp,
                                                 w, lkc, nchain, mode);
    };
    auto REDU = [&](const float* Aadd, float* Cout, float alpha, float beta,
                    float* V, const float* CPp, int w, int kc, int nR) {
        k_redu<<<1024 + nR, 256, 0, stream>>>(P0, Aadd, Cout, alpha, beta,
                                              V, CPp, w, kc, nparts);
    };

    k_scale<<<4096, 256, 0, stream>>>(A, logd, M1);      // M1 = e = (d/2)A
    // D1 = 2(e+e^2)(I+e^2+e^4):
    FUSED(M1, M1, nullptr, nullptr, 0, 0, 0, 0);
    REDU(M1, M2, 1.f, 0.f, nullptr, nullptr, 0, 0, 0);            // M2 = e^2
    k_add<<<4096, 256, 0, stream>>>(M1, M2, M1);                  // M1 = e+e^2
    FUSED(M2, M2, nullptr, nullptr, 0, 0, 0, 0);
    REDU(M2, M2, 1.f, 1.f, nullptr, nullptr, 0, 0, 0);            // M2 = e^2+e^4 (in-place)
    FUSED(M1, M2, nullptr, nullptr, 0, 0, 0, 0);
    REDU(M1, M2, 2.f, 2.f, nullptr, nullptr, 0, 0, 0);            // M2 = D1

    // init: Q[0] = d*(B + 0.5*D1@B); P[0] = C
    k_cpart<<<256, 256, 0, stream>>>(M2, (float*)Bv, CP, 1, 4, 0);
    k_initR<<<4, 256, 0, stream>>>(Bv, Cv, logd, CP, Q, P);

    float* cur = M2;
    float* nxt = M1;
    // Q loop: chain step w=2^k with D_{2^k}, fused with squaring -> D_{2^{k+1}}
    for (int k = 0; k < 7; ++k) {
        int w = 1 << k;
        int lkc = (w < 16) ? (4 - k) : 0;
        int kc = 1 << lkc;
        int nchain = 16 * kc * w;
        int nR = (kc > 1) ? 4 * w : 0;
        FUSED(cur, cur, Q, CP, w, lkc, nchain, 0);
        REDU(cur, nxt, 1.f, 2.f, Q, CP, w, kc, nR);
        float* tsw = cur; cur = nxt; nxt = tsw;
    }
    // P loop: k=0..5 fused with squarings (D_128..D_4096 -> up to D_8192)
    for (int k = 0; k < 6; ++k) {
        int w = 1 << k;
        int lkc = (w < 16) ? (4 - k) : 0;
        int kc = 1 << lkc;
        int nchain = 16 * kc * w;
        int nR = (kc > 1) ? 4 * w : 0;
        FUSED(cur, cur, P, CP, w, lkc, nchain, 1);
        REDU(cur, nxt, 1.f, 2.f, P, CP, w, kc, nR);
        float* tsw = cur; cur = nxt; nxt = tsw;
    }
    // final P step: w=64 with D_8192, direct write
    k_cpart<<<1024, 256, 0, stream>>>(cur, P, CP, 64, 0, 1);

    k_kdot<<<4096, 256, 0, stream>>>(P, Q, Kc);
    k_conv1<<<544, 256, 0, stream>>>(X, Kc, P0);
    k_conv2<<<16, 256, 0, stream>>>(X, P0, Dp, Y);
}

// Round 8
// 1027.087 us; speedup vs baseline: 2.6208x; 2.6208x over previous
//
#include <hip/hip_runtime.h>
#include <math.h>

#define N1 1024
#define NN2 (N1*N1)
#define LL 16384
#define SPLITK 4          // K split for the 1024^3 GEMMs
#define KSLAB (N1/SPLITK) // 256
#define BK 16             // k-block depth
#define NKB (KSLAB/BK)    // 16 k-blocks per slab
#define TMR 128           // tile rows
#define TNC 128           // tile cols
#define LDR 141           // LDS row stride: 128 + 4-per-32 pad + 1 (k-group bank shift)
// LDS budget: As+Bs = 2*2*16*141*4 = 36096 B; pad to EXACTLY 54272 B (rounds 4-7
// proven 128-VGPR-budget shape for 512-thread blocks) with a 4544-float region
// that hosts the chain path's sV/red.
#define PADF 4544

// ---------------- elementwise ----------------
__global__ __launch_bounds__(256) void k_scale(const float* __restrict__ A,
                                               const float* __restrict__ logd,
                                               float* __restrict__ e) {
    int i = blockIdx.x * 256 + threadIdx.x;
    float d = expf(logd[0]);
    e[i] = 0.5f * d * A[i];
}

__global__ __launch_bounds__(256) void k_add(const float* __restrict__ a,
                                             const float* __restrict__ b,
                                             float* __restrict__ o) {
    int i = blockIdx.x * 256 + threadIdx.x;
    o[i] = a[i] + b[i];
}

// ---------------- chain-partial device code (mode 0 = Q rows, 1 = P cols) --------
// NW = number of waves in the block (4 for 256-thread kernels, 8 for 512-thread).
template<int NW>
__device__ __forceinline__ void chain_part(const float* __restrict__ M,
                                           float* __restrict__ V,
                                           float* __restrict__ CP,
                                           int w, int lkc, int mode, int cb,
                                           float* sV, float (*red)[64]) {
    int kc = 1 << lkc;
    int i = cb >> (4 + lkc);
    int ky = (cb >> 4) & (kc - 1);
    int nx = cb & 15;
    int mlen = N1 >> lkc;
    int m0 = ky * mlen, n0 = nx * 64;
    int t = threadIdx.x;
    const float* Vi = V + (size_t)i * N1 + m0;
    if (t * 4 < mlen) *(float4*)&sV[t * 4] = *(const float4*)&Vi[t * 4];
    __syncthreads();
    int wave = t >> 6, lane = t & 63;
    if (mode == 0) {
        const int RR = 64 / NW;
        for (int rr = 0; rr < RR; ++rr) {
            int n = n0 + wave * RR + rr;
            const float* Mr = M + (size_t)n * N1 + m0;
            float acc = 0.f;
            for (int m = lane * 4; m < mlen; m += 256) {
                float4 a = *(const float4*)&Mr[m];
                float4 v = *(const float4*)&sV[m];
                acc += a.x * v.x + a.y * v.y + a.z * v.z + a.w * v.w;
            }
#pragma unroll
            for (int off = 32; off > 0; off >>= 1) acc += __shfl_down(acc, off, 64);
            if (lane == 0) {
                if (kc == 1) V[(size_t)(w + i) * N1 + n] = sV[n] + acc;
                else CP[((size_t)i * kc + ky) * N1 + n] = acc;
            }
        }
    } else {
        int n = n0 + lane;
        int msub = mlen / NW;
        int mb = wave * msub;
        float acc = 0.f;
#pragma unroll 8
        for (int m = 0; m < msub; ++m)
            acc += sV[mb + m] * M[(size_t)(m0 + mb + m) * N1 + n];
        red[wave][lane] = acc;
        __syncthreads();
        if (t < 64) {
            float s = 0.f;
#pragma unroll
            for (int c = 0; c < NW; ++c) s += red[c][t];
            if (kc == 1) V[(size_t)(w + i) * N1 + n0 + t] = sV[n0 + t] + s;
            else CP[((size_t)i * kc + ky) * N1 + n0 + t] = s;
        }
    }
}

// ========== fused dispatch: [chain blocks | 256 SGEMM blocks], 512 threads ==========
// GEMM: part[z] = Ain[:, z*256:(z+1)*256] @ Bin[z*256:..., :]
// 128x128 tile, BK=16, 8x4 microtile, 8 waves/block = 2 waves/SIMD GUARANTEED,
// grid 256 = exactly 1 WG/CU (no packing uncertainty).
// VGPR need ~80-95 <= the 128 budget PROVEN granted at this thread/LDS shape
// (rounds 4-7: 512 thr + 54272 B LDS -> VGPR budget 128) -> no spill.
// LDS:VALU per wave per k = 36:64 cyc -> VALUBusy cap ~44% (vs round-1's 33%).
__global__ __launch_bounds__(512)
void k_fused(const float* __restrict__ Ain,
             const float* __restrict__ Bin,
             float* __restrict__ part,
             float* __restrict__ V,
             float* __restrict__ CP,
             int w, int lkc, int nchain, int mode) {
    __shared__ __align__(16) float As[2][BK][LDR];
    __shared__ __align__(16) float Bs[2][BK][LDR];
    __shared__ __align__(16) float ldspad[PADF];   // pads LDS to 54272 B; chain sV/red
    int b = blockIdx.x;
    if (b < nchain) {
        float* sV = ldspad;                        // 1024 floats
        float (*red)[64] = (float(*)[64])(ldspad + N1);  // 8*64 = 512 floats
        chain_part<8>(Ain, V, CP, w, lkc, mode, b, sV, red);
        return;
    }
    int g = b - nchain;
    int t = threadIdx.x;
    int z = g >> 6;
    int tile = g & 63;
    int m0 = (tile >> 3) * TMR, n0 = (tile & 7) * TNC, kz = z * KSLAB;
    int tx = t & 31, ty = t >> 5;   // 32 col-groups x 16 row-groups

    // global-load mapping: A 128 rows x 16 k (4 floats/thread), B 16 k x 128 cols (4/thread)
    int arow = t >> 2, acol = (t & 3) * 4;
    int brow = t >> 5, bcol = (t & 31) * 4;
    const float* Ap = Ain + (size_t)(m0 + arow) * N1 + kz + acol;
    const float* Bp = Bin + (size_t)(kz + brow) * N1 + n0 + bcol;

    // padded physical column indices (+4 per 32)
    int aphys = arow + ((arow >> 5) << 2);
    int bphys = bcol + ((bcol >> 5) << 2);
    int afrag = ty * 8 + ((ty >> 2) << 2);   // phys(ty*8); +4 stays in same pad group
    int bfrag = tx * 4 + ((tx >> 3) << 2);   // phys(tx*4)

    { // prologue: stage k-block 0
        float4 a0 = *(const float4*)(Ap);
        float4 b0 = *(const float4*)(Bp);
        As[0][acol + 0][aphys] = a0.x; As[0][acol + 1][aphys] = a0.y;
        As[0][acol + 2][aphys] = a0.z; As[0][acol + 3][aphys] = a0.w;
        *(float4*)&Bs[0][brow][bphys] = b0;
    }
    __syncthreads();

    float acc[8][4];
#pragma unroll
    for (int i = 0; i < 8; ++i)
#pragma unroll
        for (int j = 0; j < 4; ++j) acc[i][j] = 0.f;

    for (int kb = 0; kb < NKB; ++kb) {
        int cur = kb & 1;
        float4 na0, nb0;
        if (kb < NKB - 1) {
            int ko = (kb + 1) * BK;
            na0 = *(const float4*)(Ap + ko);
            nb0 = *(const float4*)(Bp + (size_t)ko * N1);
        }
#pragma unroll
        for (int k = 0; k < BK; ++k) {
            float4 xa0 = *(float4*)&As[cur][k][afrag];
            float4 xa1 = *(float4*)&As[cur][k][afrag + 4];
            float4 xb0 = *(float4*)&Bs[cur][k][bfrag];
            float av[8] = {xa0.x, xa0.y, xa0.z, xa0.w, xa1.x, xa1.y, xa1.z, xa1.w};
            float bv[4] = {xb0.x, xb0.y, xb0.z, xb0.w};
#pragma unroll
            for (int i = 0; i < 8; ++i)
#pragma unroll
                for (int j = 0; j < 4; ++j) acc[i][j] += av[i] * bv[j];
        }
        if (kb < NKB - 1) {
            int nx2 = cur ^ 1;
            As[nx2][acol + 0][aphys] = na0.x; As[nx2][acol + 1][aphys] = na0.y;
            As[nx2][acol + 2][aphys] = na0.z; As[nx2][acol + 3][aphys] = na0.w;
            *(float4*)&Bs[nx2][brow][bphys] = nb0;
            __syncthreads();
        }
    }

    float* Po = part + (size_t)z * NN2;
#pragma unroll
    for (int i = 0; i < 8; ++i) {
        float4 o0 = {acc[i][0], acc[i][1], acc[i][2], acc[i][3]};
        *(float4*)&Po[(size_t)(m0 + ty * 8 + i) * N1 + n0 + tx * 4] = o0;
    }
}

// ---------------- chain-partial-only dispatch (init Q0, final P step), 256 thr ----
__global__ __launch_bounds__(256) void k_cpart(const float* __restrict__ M,
                                               float* __restrict__ V,
                                               float* __restrict__ CP,
                                               int w, int lkc, int mode) {
    __shared__ float sV[N1];
    __shared__ float red[4][64];
    chain_part<4>(M, V, CP, w, lkc, mode, blockIdx.x, sV, red);
}

// ---------------- fused reduce: [1024 mmred blocks | 4w chainR blocks] ------------
// mmred: Cout = alpha*sum(part[0..nparts)) + beta*Aadd
__global__ __launch_bounds__(256) void k_redu(const float* __restrict__ part,
                                              const float* __restrict__ Aadd,
                                              float* __restrict__ C,
                                              float alpha, float beta,
                                              float* __restrict__ V,
                                              const float* __restrict__ CP,
                                              int w, int kc, int nparts) {
    int b = blockIdx.x, t = threadIdx.x;
    if (b < 1024) {
        int i = (b * 256 + t) * 4;
        float sx = 0.f, sy = 0.f, sz = 0.f, sw = 0.f;
        for (int c = 0; c < nparts; ++c) {
            float4 p = *(const float4*)&part[(size_t)c * NN2 + i];
            sx += p.x; sy += p.y; sz += p.z; sw += p.w;
        }
        float4 av = *(const float4*)&Aadd[i];
        float4 o;
        o.x = alpha * sx + beta * av.x;
        o.y = alpha * sy + beta * av.y;
        o.z = alpha * sz + beta * av.z;
        o.w = alpha * sw + beta * av.w;
        *(float4*)&C[i] = o;
    } else {
        int rb = b - 1024;
        int i = rb >> 2;
        int n = (rb & 3) * 256 + t;
        const float* pp = CP + (size_t)i * kc * N1 + n;
        float s = 0.f;
        for (int c = 0; c < kc; ++c) s += pp[(size_t)c * N1];
        V[(size_t)(w + i) * N1 + n] = V[(size_t)i * N1 + n] + s;
    }
}

// ---------------- init reduce: Q[0] = d*(B + 0.5*D1@B); P[0] = C ----------------
__global__ __launch_bounds__(256) void k_initR(const float* __restrict__ Bv,
                                               const float* __restrict__ Cv,
                                               const float* __restrict__ logd,
                                               const float* __restrict__ part,
                                               float* __restrict__ Q,
                                               float* __restrict__ P) {
    int n = blockIdx.x * 256 + threadIdx.x;
    float s = 0.f;
    for (int c = 0; c < 16; ++c) s += part[(size_t)c * N1 + n];
    float d = expf(logd[0]);
    Q[n] = d * (Bv[n] + 0.5f * s);
    P[n] = Cv[n];
}

// ---------------- K[a*128+b] = dot(P[a], Q[b]) ----------------
__global__ __launch_bounds__(256) void k_kdot(const float* __restrict__ P,
                                              const float* __restrict__ Q,
                                              float* __restrict__ K) {
    int t = threadIdx.x;
    int wid = blockIdx.x * 4 + (t >> 6), lane = t & 63;
    int a = wid >> 7, b = wid & 127;
    const float* Pr = P + (size_t)a * N1;
    const float* Qr = Q + (size_t)b * N1;
    float acc = 0.f;
#pragma unroll
    for (int jj = 0; jj < 4; ++jj) {
        int m = jj * 256 + lane * 4;
        float4 p = *(const float4*)&Pr[m];
        float4 q = *(const float4*)&Qr[m];
        acc += p.x * q.x + p.y * q.y + p.z * q.z + p.w * q.w;
    }
#pragma unroll
    for (int off = 32; off > 0; off >>= 1) acc += __shfl_down(acc, off, 64);
    if (lane == 0) K[wid] = acc;
}

// ---------------- conv phase 1 ----------------
__global__ __launch_bounds__(256) void k_conv1(const float* __restrict__ X,
                                               const float* __restrict__ K,
                                               float* __restrict__ part) {
    __shared__ __align__(16) float ks[1280];
    __shared__ __align__(16) float xs[256];
    int bx = blockIdx.x, tt = threadIdx.x;
    int o = 0;
    while (bx >= 2 * (o + 1) * (o + 1) + 2 * (o + 1)) ++o;
    int jt = bx - (2 * o * o + 2 * o);
    int T0 = o * 1024, J0 = jt * 256;
    int mb = T0 - J0 - 255;
    for (int ii = tt; ii < 1280; ii += 256) {
        int m = mb + ii;
        ks[ii] = (m >= 0 && m < LL) ? K[m] : 0.f;
    }
    xs[tt] = X[J0 + tt];
    __syncthreads();

    float acc0 = 0.f, acc1 = 0.f, acc2 = 0.f, acc3 = 0.f;
    int base0 = 4 * tt + 252;
#pragma unroll 4
    for (int jj = 0; jj < 256; jj += 4) {
        float4 xv  = *(const float4*)&xs[jj];
        float4 kv0 = *(const float4*)&ks[base0 - jj];
        float4 kv1 = *(const float4*)&ks[base0 - jj + 4];
        float kk0 = kv0.x, kk1 = kv0.y, kk2 = kv0.z, kk3 = kv0.w;
        float kk4 = kv1.x, kk5 = kv1.y, kk6 = kv1.z;
        acc0 += kk3 * xv.x + kk2 * xv.y + kk1 * xv.z + kk0 * xv.w;
        acc1 += kk4 * xv.x + kk3 * xv.y + kk2 * xv.z + kk1 * xv.w;
        acc2 += kk5 * xv.x + kk4 * xv.y + kk3 * xv.z + kk2 * xv.w;
        acc3 += kk6 * xv.x + kk5 * xv.y + kk4 * xv.z + kk3 * xv.w;
    }
    float4 out = {acc0, acc1, acc2, acc3};
    *(float4*)&part[((size_t)(o * 64 + jt)) * 1024 + 4 * tt] = out;
}

// ---------------- conv phase 2 ----------------
__global__ __launch_bounds__(256) void k_conv2(const float* __restrict__ X,
                                               const float* __restrict__ part,
                                               const float* __restrict__ Dp,
                                               float* __restrict__ Y) {
    int o = blockIdx.x, tt = threadIdx.x;
    int c = 4 * tt;
    float s0 = 0.f, s1 = 0.f, s2 = 0.f, s3 = 0.f;
    int cnt = 4 * o + 4;
    for (int jt = 0; jt < cnt; ++jt) {
        float4 p = *(const float4*)&part[((size_t)(o * 64 + jt)) * 1024 + c];
        s0 += p.x; s1 += p.y; s2 += p.z; s3 += p.w;
    }
    float dsk = Dp[0];
    int t = o * 1024 + c;
    float4 xv = *(const float4*)&X[t];
    float4 out;
    out.x = dsk * xv.x + s0;
    out.y = dsk * xv.y + s1;
    out.z = dsk * xv.z + s2;
    out.w = dsk * xv.w + s3;
    *(float4*)&Y[t] = out;
}

extern "C" void kernel_launch(void* const* d_in, const int* in_sizes, int n_in,
                              void* d_out, int out_size, void* d_ws, size_t ws_size,
                              hipStream_t stream) {
    const float* X    = (const float*)d_in[0];
    const float* A    = (const float*)d_in[1];
    const float* Bv   = (const float*)d_in[2];
    const float* Cv   = (const float*)d_in[3];
    const float* Dp   = (const float*)d_in[4];
    const float* logd = (const float*)d_in[5];
    float* ws = (float*)d_ws;

    const int nparts = SPLITK;         // 4
    const int NG = 64 * SPLITK;        // 256 GEMM blocks = exactly 1 WG/CU

    // layout: [partials (4 x NN2)] [M1] [M2] [CP] [Q] [P] [Kc]
    float* P0 = ws;
    float* M1 = ws + (size_t)nparts * NN2;
    float* M2 = M1 + (size_t)NN2;
    float* CP = M2 + (size_t)NN2;          // chain partials (<=64 KB)
    float* Q  = CP + 64*(size_t)N1;        // 128 x 1024
    float* P  = Q + 128*(size_t)N1;        // 128 x 1024
    float* Kc = P + 128*(size_t)N1;        // 16384
    float* Y  = (float*)d_out;

    auto FUSED = [&](const float* Aq, const float* Bq, float* V, float* CPp,
                     int w, int lkc, int nchain, int mode) {
        k_fused<<<nchain + NG, 512, 0, stream>>>(Aq, Bq, P0, V, CPp,
                                                 w, lkc, nchain, mode);
    };
    auto REDU = [&](const float* Aadd, float* Cout, float alpha, float beta,
                    float* V, const float* CPp, int w, int kc, int nR) {
        k_redu<<<1024 + nR, 256, 0, stream>>>(P0, Aadd, Cout, alpha, beta,
                                              V, CPp, w, kc, nparts);
    };

    k_scale<<<4096, 256, 0, stream>>>(A, logd, M1);      // M1 = e = (d/2)A
    // D1 = 2(e+e^2)(I+e^2+e^4):
    FUSED(M1, M1, nullptr, nullptr, 0, 0, 0, 0);
    REDU(M1, M2, 1.f, 0.f, nullptr, nullptr, 0, 0, 0);            // M2 = e^2
    k_add<<<4096, 256, 0, stream>>>(M1, M2, M1);                  // M1 = e+e^2
    FUSED(M2, M2, nullptr, nullptr, 0, 0, 0, 0);
    REDU(M2, M2, 1.f, 1.f, nullptr, nullptr, 0, 0, 0);            // M2 = e^2+e^4 (in-place)
    FUSED(M1, M2, nullptr, nullptr, 0, 0, 0, 0);
    REDU(M1, M2, 2.f, 2.f, nullptr, nullptr, 0, 0, 0);            // M2 = D1

    // init: Q[0] = d*(B + 0.5*D1@B); P[0] = C
    k_cpart<<<256, 256, 0, stream>>>(M2, (float*)Bv, CP, 1, 4, 0);
    k_initR<<<4, 256, 0, stream>>>(Bv, Cv, logd, CP, Q, P);

    float* cur = M2;
    float* nxt = M1;
    // Q loop: chain step w=2^k with D_{2^k}, fused with squaring -> D_{2^{k+1}}
    for (int k = 0; k < 7; ++k) {
        int w = 1 << k;
        int lkc = (w < 16) ? (4 - k) : 0;
        int kc = 1 << lkc;
        int nchain = 16 * kc * w;
        int nR = (kc > 1) ? 4 * w : 0;
        FUSED(cur, cur, Q, CP, w, lkc, nchain, 0);
        REDU(cur, nxt, 1.f, 2.f, Q, CP, w, kc, nR);
        float* tsw = cur; cur = nxt; nxt = tsw;
    }
    // P loop: k=0..5 fused with squarings (D_128..D_4096 -> up to D_8192)
    for (int k = 0; k < 6; ++k) {
        int w = 1 << k;
        int lkc = (w < 16) ? (4 - k) : 0;
        int kc = 1 << lkc;
        int nchain = 16 * kc * w;
        int nR = (kc > 1) ? 4 * w : 0;
        FUSED(cur, cur, P, CP, w, lkc, nchain, 1);
        REDU(cur, nxt, 1.f, 2.f, P, CP, w, kc, nR);
        float* tsw = cur; cur = nxt; nxt = tsw;
    }
    // final P step: w=64 with D_8192, direct write
    k_cpart<<<1024, 256, 0, stream>>>(cur, P, CP, 64, 0, 1);

    k_kdot<<<4096, 256, 0, stream>>>(P, Q, Kc);
    k_conv1<<<544, 256, 0, stream>>>(X, Kc, P0);
    k_conv2<<<16, 256, 0, stream>>>(X, P0, Dp, Y);
}

// Round 9
// 899.092 us; speedup vs baseline: 2.9939x; 1.1424x over previous
//
#include <hip/hip_runtime.h>
#include <math.h>

#define N1 1024
#define NN2 (N1*N1)
#define LL 16384
#define SPLITK 8          // K split for the 1024^3 GEMMs
#define KSLAB (N1/SPLITK) // 128
#define BK 16             // k-block depth
#define NKB (KSLAB/BK)    // 8 k-blocks per slab
#define TMR 128           // tile rows
#define TNC 64            // tile cols
#define ASTR 141          // As row stride (128 + 4-per-32 pad + 1 bank shift)
#define BSTR 72           // Bs row stride (64 + 4-per-32 pad + 4)
// LDS: As 2*16*141=4512f, Bs 2*16*72=2304f, pad 2400f -> 9216 f = 36864 B exactly.
// 160K/36864 = 4 WGs occupancy target -> 128-VGPR budget (R1/R4-7 calibration);
// 4 WGs x 36864 = 147456 <= 163840 so 4 WGs/CU also FIT. Pad hosts chain sV/red.
#define PADF 2400

// ---------------- elementwise ----------------
__global__ __launch_bounds__(256) void k_scale(const float* __restrict__ A,
                                               const float* __restrict__ logd,
                                               float* __restrict__ e) {
    int i = blockIdx.x * 256 + threadIdx.x;
    float d = expf(logd[0]);
    e[i] = 0.5f * d * A[i];
}

__global__ __launch_bounds__(256) void k_add(const float* __restrict__ a,
                                             const float* __restrict__ b,
                                             float* __restrict__ o) {
    int i = blockIdx.x * 256 + threadIdx.x;
    o[i] = a[i] + b[i];
}

// ---------------- chain-partial device code (mode 0 = Q rows, 1 = P cols) --------
template<int NW>
__device__ __forceinline__ void chain_part(const float* __restrict__ M,
                                           float* __restrict__ V,
                                           float* __restrict__ CP,
                                           int w, int lkc, int mode, int cb,
                                           float* sV, float (*red)[64]) {
    int kc = 1 << lkc;
    int i = cb >> (4 + lkc);
    int ky = (cb >> 4) & (kc - 1);
    int nx = cb & 15;
    int mlen = N1 >> lkc;
    int m0 = ky * mlen, n0 = nx * 64;
    int t = threadIdx.x;
    const float* Vi = V + (size_t)i * N1 + m0;
    if (t * 4 < mlen) *(float4*)&sV[t * 4] = *(const float4*)&Vi[t * 4];
    __syncthreads();
    int wave = t >> 6, lane = t & 63;
    if (mode == 0) {
        const int RR = 64 / NW;
        for (int rr = 0; rr < RR; ++rr) {
            int n = n0 + wave * RR + rr;
            const float* Mr = M + (size_t)n * N1 + m0;
            float acc = 0.f;
            for (int m = lane * 4; m < mlen; m += 256) {
                float4 a = *(const float4*)&Mr[m];
                float4 v = *(const float4*)&sV[m];
                acc += a.x * v.x + a.y * v.y + a.z * v.z + a.w * v.w;
            }
#pragma unroll
            for (int off = 32; off > 0; off >>= 1) acc += __shfl_down(acc, off, 64);
            if (lane == 0) {
                if (kc == 1) V[(size_t)(w + i) * N1 + n] = sV[n] + acc;
                else CP[((size_t)i * kc + ky) * N1 + n] = acc;
            }
        }
    } else {
        int n = n0 + lane;
        int msub = mlen / NW;
        int mb = wave * msub;
        float acc = 0.f;
#pragma unroll 8
        for (int m = 0; m < msub; ++m)
            acc += sV[mb + m] * M[(size_t)(m0 + mb + m) * N1 + n];
        red[wave][lane] = acc;
        __syncthreads();
        if (t < 64) {
            float s = 0.f;
#pragma unroll
            for (int c = 0; c < NW; ++c) s += red[c][t];
            if (kc == 1) V[(size_t)(w + i) * N1 + n0 + t] = sV[n0 + t] + s;
            else CP[((size_t)i * kc + ky) * N1 + n0 + t] = s;
        }
    }
}

// ========== fused dispatch: [chain blocks | 1024 SGEMM blocks], 256 threads =========
// GEMM: part[z] = Ain[:, z*128:(z+1)*128] @ Bin[z*128:..., :]
// 128x64 tile, BK=16, 8x4 microtile. Grid 1024 = 4 WGs/CU offered; 256-thread
// low-VGPR blocks are the PROVEN-packing class (R1: occ 31% = 2.5 WGs/CU).
// Conflict design (R8 lesson: 32-distinct-addr b128 row reads = 4-way/phase):
//  - B-frag reads: only 16 distinct addresses (64-wide tile) -> ~2-way, free.
//  - A-frag reads: 4 addresses/wave, disjoint bank groups, 16-lane broadcast.
//  - A-staging: stride 141 -> write banks = 13*(acol+j)+row, 2 classes x 32 rows
//    cover all 32 banks twice -> 2-way, free.
__global__ __launch_bounds__(256)
void k_fused(const float* __restrict__ Ain,
             const float* __restrict__ Bin,
             float* __restrict__ part,
             float* __restrict__ V,
             float* __restrict__ CP,
             int w, int lkc, int nchain, int mode) {
    __shared__ __align__(16) float As[2][BK][ASTR];
    __shared__ __align__(16) float Bs[2][BK][BSTR];
    __shared__ __align__(16) float ldspad[PADF];   // occupancy-shaping pad + chain sV/red
    int b = blockIdx.x;
    if (b < nchain) {
        float* sV = ldspad;                          // 1024 floats
        float (*red)[64] = (float(*)[64])(ldspad + N1);  // 4*64 floats
        chain_part<4>(Ain, V, CP, w, lkc, mode, b, sV, red);
        return;
    }
    int g = b - nchain;
    int t = threadIdx.x;
    int z = g >> 7;                 // slab index (8 slabs)
    int tile = g & 127;             // 8 row-tiles x 16 col-tiles
    int m0 = (tile >> 4) * TMR, n0 = (tile & 15) * TNC, kz = z * KSLAB;
    int tx = t & 15, ty = t >> 4;

    // global-load mapping: A 128 rows x 16 k (8 f/thread), B 16 k x 64 cols (4 f/thread)
    int arow = t >> 1, acol = (t & 1) * 8;
    int brow = t >> 4, bcol = (t & 15) * 4;
    const float* Ap = Ain + (size_t)(m0 + arow) * N1 + kz + acol;
    const float* Bp = Bin + (size_t)(kz + brow) * N1 + n0 + bcol;

    // padded physical indices (+4 per 32)
    int aphys = arow + ((arow >> 5) << 2);
    int bphys = bcol + ((bcol >> 5) << 2);
    int afrag = ty * 8 + ((ty >> 2) << 2);
    int bfrag = tx * 4 + ((tx >> 3) << 2);

    { // prologue: stage k-block 0
        float4 a0 = *(const float4*)(Ap);
        float4 a1 = *(const float4*)(Ap + 4);
        float4 b0 = *(const float4*)(Bp);
        As[0][acol + 0][aphys] = a0.x; As[0][acol + 1][aphys] = a0.y;
        As[0][acol + 2][aphys] = a0.z; As[0][acol + 3][aphys] = a0.w;
        As[0][acol + 4][aphys] = a1.x; As[0][acol + 5][aphys] = a1.y;
        As[0][acol + 6][aphys] = a1.z; As[0][acol + 7][aphys] = a1.w;
        *(float4*)&Bs[0][brow][bphys] = b0;
    }
    __syncthreads();

    float acc[8][4];
#pragma unroll
    for (int i = 0; i < 8; ++i)
#pragma unroll
        for (int j = 0; j < 4; ++j) acc[i][j] = 0.f;

    for (int kb = 0; kb < NKB; ++kb) {
        int cur = kb & 1;
        float4 na0, na1, nb0;
        if (kb < NKB - 1) {
            int ko = (kb + 1) * BK;
            na0 = *(const float4*)(Ap + ko);
            na1 = *(const float4*)(Ap + ko + 4);
            nb0 = *(const float4*)(Bp + (size_t)ko * N1);
        }
#pragma unroll
        for (int k = 0; k < BK; ++k) {
            float4 xa0 = *(float4*)&As[cur][k][afrag];
            float4 xa1 = *(float4*)&As[cur][k][afrag + 4];
            float4 xb0 = *(float4*)&Bs[cur][k][bfrag];
            float av[8] = {xa0.x, xa0.y, xa0.z, xa0.w, xa1.x, xa1.y, xa1.z, xa1.w};
            float bv[4] = {xb0.x, xb0.y, xb0.z, xb0.w};
#pragma unroll
            for (int i = 0; i < 8; ++i)
#pragma unroll
                for (int j = 0; j < 4; ++j) acc[i][j] += av[i] * bv[j];
        }
        if (kb < NKB - 1) {
            int nx2 = cur ^ 1;
            As[nx2][acol + 0][aphys] = na0.x; As[nx2][acol + 1][aphys] = na0.y;
            As[nx2][acol + 2][aphys] = na0.z; As[nx2][acol + 3][aphys] = na0.w;
            As[nx2][acol + 4][aphys] = na1.x; As[nx2][acol + 5][aphys] = na1.y;
            As[nx2][acol + 6][aphys] = na1.z; As[nx2][acol + 7][aphys] = na1.w;
            *(float4*)&Bs[nx2][brow][bphys] = nb0;
            __syncthreads();
        }
    }

    float* Po = part + (size_t)z * NN2;
#pragma unroll
    for (int i = 0; i < 8; ++i) {
        float4 o0 = {acc[i][0], acc[i][1], acc[i][2], acc[i][3]};
        *(float4*)&Po[(size_t)(m0 + ty * 8 + i) * N1 + n0 + tx * 4] = o0;
    }
}

// ---------------- chain-partial-only dispatch (init Q0, final P step), 256 thr ----
__global__ __launch_bounds__(256) void k_cpart(const float* __restrict__ M,
                                               float* __restrict__ V,
                                               float* __restrict__ CP,
                                               int w, int lkc, int mode) {
    __shared__ float sV[N1];
    __shared__ float red[4][64];
    chain_part<4>(M, V, CP, w, lkc, mode, blockIdx.x, sV, red);
}

// ---------------- fused reduce: [1024 mmred blocks | 4w chainR blocks] ------------
// mmred: Cout = alpha*sum(part[0..nparts)) + beta*Aadd
__global__ __launch_bounds__(256) void k_redu(const float* __restrict__ part,
                                              const float* __restrict__ Aadd,
                                              float* __restrict__ C,
                                              float alpha, float beta,
                                              float* __restrict__ V,
                                              const float* __restrict__ CP,
                                              int w, int kc, int nparts) {
    int b = blockIdx.x, t = threadIdx.x;
    if (b < 1024) {
        int i = (b * 256 + t) * 4;
        float sx = 0.f, sy = 0.f, sz = 0.f, sw = 0.f;
        for (int c = 0; c < nparts; ++c) {
            float4 p = *(const float4*)&part[(size_t)c * NN2 + i];
            sx += p.x; sy += p.y; sz += p.z; sw += p.w;
        }
        float4 av = *(const float4*)&Aadd[i];
        float4 o;
        o.x = alpha * sx + beta * av.x;
        o.y = alpha * sy + beta * av.y;
        o.z = alpha * sz + beta * av.z;
        o.w = alpha * sw + beta * av.w;
        *(float4*)&C[i] = o;
    } else {
        int rb = b - 1024;
        int i = rb >> 2;
        int n = (rb & 3) * 256 + t;
        const float* pp = CP + (size_t)i * kc * N1 + n;
        float s = 0.f;
        for (int c = 0; c < kc; ++c) s += pp[(size_t)c * N1];
        V[(size_t)(w + i) * N1 + n] = V[(size_t)i * N1 + n] + s;
    }
}

// ---------------- init reduce: Q[0] = d*(B + 0.5*D1@B); P[0] = C ----------------
__global__ __launch_bounds__(256) void k_initR(const float* __restrict__ Bv,
                                               const float* __restrict__ Cv,
                                               const float* __restrict__ logd,
                                               const float* __restrict__ part,
                                               float* __restrict__ Q,
                                               float* __restrict__ P) {
    int n = blockIdx.x * 256 + threadIdx.x;
    float s = 0.f;
    for (int c = 0; c < 16; ++c) s += part[(size_t)c * N1 + n];
    float d = expf(logd[0]);
    Q[n] = d * (Bv[n] + 0.5f * s);
    P[n] = Cv[n];
}

// ---------------- K[a*128+b] = dot(P[a], Q[b]) ----------------
__global__ __launch_bounds__(256) void k_kdot(const float* __restrict__ P,
                                              const float* __restrict__ Q,
                                              float* __restrict__ K) {
    int t = threadIdx.x;
    int wid = blockIdx.x * 4 + (t >> 6), lane = t & 63;
    int a = wid >> 7, b = wid & 127;
    const float* Pr = P + (size_t)a * N1;
    const float* Qr = Q + (size_t)b * N1;
    float acc = 0.f;
#pragma unroll
    for (int jj = 0; jj < 4; ++jj) {
        int m = jj * 256 + lane * 4;
        float4 p = *(const float4*)&Pr[m];
        float4 q = *(const float4*)&Qr[m];
        acc += p.x * q.x + p.y * q.y + p.z * q.z + p.w * q.w;
    }
#pragma unroll
    for (int off = 32; off > 0; off >>= 1) acc += __shfl_down(acc, off, 64);
    if (lane == 0) K[wid] = acc;
}

// ---------------- conv phase 1 ----------------
__global__ __launch_bounds__(256) void k_conv1(const float* __restrict__ X,
                                               const float* __restrict__ K,
                                               float* __restrict__ part) {
    __shared__ __align__(16) float ks[1280];
    __shared__ __align__(16) float xs[256];
    int bx = blockIdx.x, tt = threadIdx.x;
    int o = 0;
    while (bx >= 2 * (o + 1) * (o + 1) + 2 * (o + 1)) ++o;
    int jt = bx - (2 * o * o + 2 * o);
    int T0 = o * 1024, J0 = jt * 256;
    int mb = T0 - J0 - 255;
    for (int ii = tt; ii < 1280; ii += 256) {
        int m = mb + ii;
        ks[ii] = (m >= 0 && m < LL) ? K[m] : 0.f;
    }
    xs[tt] = X[J0 + tt];
    __syncthreads();

    float acc0 = 0.f, acc1 = 0.f, acc2 = 0.f, acc3 = 0.f;
    int base0 = 4 * tt + 252;
#pragma unroll 4
    for (int jj = 0; jj < 256; jj += 4) {
        float4 xv  = *(const float4*)&xs[jj];
        float4 kv0 = *(const float4*)&ks[base0 - jj];
        float4 kv1 = *(const float4*)&ks[base0 - jj + 4];
        float kk0 = kv0.x, kk1 = kv0.y, kk2 = kv0.z, kk3 = kv0.w;
        float kk4 = kv1.x, kk5 = kv1.y, kk6 = kv1.z;
        acc0 += kk3 * xv.x + kk2 * xv.y + kk1 * xv.z + kk0 * xv.w;
        acc1 += kk4 * xv.x + kk3 * xv.y + kk2 * xv.z + kk1 * xv.w;
        acc2 += kk5 * xv.x + kk4 * xv.y + kk3 * xv.z + kk2 * xv.w;
        acc3 += kk6 * xv.x + kk5 * xv.y + kk4 * xv.z + kk3 * xv.w;
    }
    float4 out = {acc0, acc1, acc2, acc3};
    *(float4*)&part[((size_t)(o * 64 + jt)) * 1024 + 4 * tt] = out;
}

// ---------------- conv phase 2 ----------------
__global__ __launch_bounds__(256) void k_conv2(const float* __restrict__ X,
                                               const float* __restrict__ part,
                                               const float* __restrict__ Dp,
                                               float* __restrict__ Y) {
    int o = blockIdx.x, tt = threadIdx.x;
    int c = 4 * tt;
    float s0 = 0.f, s1 = 0.f, s2 = 0.f, s3 = 0.f;
    int cnt = 4 * o + 4;
    for (int jt = 0; jt < cnt; ++jt) {
        float4 p = *(const float4*)&part[((size_t)(o * 64 + jt)) * 1024 + c];
        s0 += p.x; s1 += p.y; s2 += p.z; s3 += p.w;
    }
    float dsk = Dp[0];
    int t = o * 1024 + c;
    float4 xv = *(const float4*)&X[t];
    float4 out;
    out.x = dsk * xv.x + s0;
    out.y = dsk * xv.y + s1;
    out.z = dsk * xv.z + s2;
    out.w = dsk * xv.w + s3;
    *(float4*)&Y[t] = out;
}

extern "C" void kernel_launch(void* const* d_in, const int* in_sizes, int n_in,
                              void* d_out, int out_size, void* d_ws, size_t ws_size,
                              hipStream_t stream) {
    const float* X    = (const float*)d_in[0];
    const float* A    = (const float*)d_in[1];
    const float* Bv   = (const float*)d_in[2];
    const float* Cv   = (const float*)d_in[3];
    const float* Dp   = (const float*)d_in[4];
    const float* logd = (const float*)d_in[5];
    float* ws = (float*)d_ws;

    const int nparts = SPLITK;         // 8 (ws >= 10*NN2+extras proven R3-R7)
    const int NG = 128 * SPLITK;       // 1024 GEMM blocks = 4 WGs/CU offered

    // layout: [partials (8 x NN2)] [M1] [M2] [CP] [Q] [P] [Kc]
    float* P0 = ws;
    float* M1 = ws + (size_t)nparts * NN2;
    float* M2 = M1 + (size_t)NN2;
    float* CP = M2 + (size_t)NN2;          // chain partials (<=64 KB)
    float* Q  = CP + 64*(size_t)N1;        // 128 x 1024
    float* P  = Q + 128*(size_t)N1;        // 128 x 1024
    float* Kc = P + 128*(size_t)N1;        // 16384
    float* Y  = (float*)d_out;

    auto FUSED = [&](const float* Aq, const float* Bq, float* V, float* CPp,
                     int w, int lkc, int nchain, int mode) {
        k_fused<<<nchain + NG, 256, 0, stream>>>(Aq, Bq, P0, V, CPp,
                                                 w, lkc, nchain, mode);
    };
    auto REDU = [&](const float* Aadd, float* Cout, float alpha, float beta,
                    float* V, const float* CPp, int w, int kc, int nR) {
        k_redu<<<1024 + nR, 256, 0, stream>>>(P0, Aadd, Cout, alpha, beta,
                                              V, CPp, w, kc, nparts);
    };

    k_scale<<<4096, 256, 0, stream>>>(A, logd, M1);      // M1 = e = (d/2)A
    // D1 = 2(e+e^2)(I+e^2+e^4):
    FUSED(M1, M1, nullptr, nullptr, 0, 0, 0, 0);
    REDU(M1, M2, 1.f, 0.f, nullptr, nullptr, 0, 0, 0);            // M2 = e^2
    k_add<<<4096, 256, 0, stream>>>(M1, M2, M1);                  // M1 = e+e^2
    FUSED(M2, M2, nullptr, nullptr, 0, 0, 0, 0);
    REDU(M2, M2, 1.f, 1.f, nullptr, nullptr, 0, 0, 0);            // M2 = e^2+e^4 (in-place)
    FUSED(M1, M2, nullptr, nullptr, 0, 0, 0, 0);
    REDU(M1, M2, 2.f, 2.f, nullptr, nullptr, 0, 0, 0);            // M2 = D1

    // init: Q[0] = d*(B + 0.5*D1@B); P[0] = C
    k_cpart<<<256, 256, 0, stream>>>(M2, (float*)Bv, CP, 1, 4, 0);
    k_initR<<<4, 256, 0, stream>>>(Bv, Cv, logd, CP, Q, P);

    float* cur = M2;
    float* nxt = M1;
    // Q loop: chain step w=2^k with D_{2^k}, fused with squaring -> D_{2^{k+1}}
    for (int k = 0; k < 7; ++k) {
        int w = 1 << k;
        int lkc = (w < 16) ? (4 - k) : 0;
        int kc = 1 << lkc;
        int nchain = 16 * kc * w;
        int nR = (kc > 1) ? 4 * w : 0;
        FUSED(cur, cur, Q, CP, w, lkc, nchain, 0);
        REDU(cur, nxt, 1.f, 2.f, Q, CP, w, kc, nR);
        float* tsw = cur; cur = nxt; nxt = tsw;
    }
    // P loop: k=0..5 fused with squarings (D_128..D_4096 -> up to D_8192)
    for (int k = 0; k < 6; ++k) {
        int w = 1 << k;
        int lkc = (w < 16) ? (4 - k) : 0;
        int kc = 1 << lkc;
        int nchain = 16 * kc * w;
        int nR = (kc > 1) ? 4 * w : 0;
        FUSED(cur, cur, P, CP, w, lkc, nchain, 1);
        REDU(cur, nxt, 1.f, 2.f, P, CP, w, kc, nR);
        float* tsw = cur; cur = nxt; nxt = tsw;
    }
    // final P step: w=64 with D_8192, direct write
    k_cpart<<<1024, 256, 0, stream>>>(cur, P, CP, 64, 0, 1);

    k_kdot<<<4096, 256, 0, stream>>>(P, Q, Kc);
    k_conv1<<<544, 256, 0, stream>>>(X, Kc, P0);
    k_conv2<<<16, 256, 0, stream>>>(X, P0, Dp, Y);
}